// Round 9
// baseline (952.416 us; speedup 1.0000x reference)
//
#include <hip/hip_runtime.h>
#include <math.h>

#define N_NODES 50000
#define N_PAD   50048            // padded rows for 128-row GEMM tiles
#define E_EDGES 1600000
#define ETOT    (E_EDGES + N_NODES)
#define EPAD    (E_EDGES + 8 * N_NODES)   // CSR rows padded to multiple of 8
#define IN_DIM  300
#define KP1     320              // IN_DIM padded to mult of 32
#define HID     256
#define HEADS   8
#define OC      32
#define LAYERS  4
#define BSAMP   1024
#define NEG_SLOPE 0.2f
#define DEG_CAP 128              // fast-path max padded degree per node

// XCD-bucketed CSR build
#define NB     8                 // buckets = XCDs
#define NPB    6250              // nodes per bucket (50000/8)
#define BCAP   262144            // per-bucket partition capacity (mean 206k)
#define NBLK_P 512               // partition blocks
#define NBLK_S 196               // scan blocks (50000/256 rounded up)

typedef unsigned long long ull;
typedef _Float16 half8 __attribute__((ext_vector_type(8)));
typedef _Float16 half4v __attribute__((ext_vector_type(4)));
typedef float f32x4 __attribute__((ext_vector_type(4)));

#define GLDS16(g, l) __builtin_amdgcn_global_load_lds( \
    (const __attribute__((address_space(1))) void*)(g), \
    (__attribute__((address_space(3))) void*)(l), 16, 0, 0)

// ---------------------------------------------------------------- CSR build
// Two-pass block-local radix partition by tgt bucket. No global atomics.

__global__ __launch_bounds__(256) void part_count_kernel(const int* __restrict__ tgt,
                                                         int* __restrict__ gcount) {
    __shared__ int cnt[NB];
    if (threadIdx.x < NB) cnt[threadIdx.x] = 0;
    __syncthreads();
    const int chunk = (ETOT + NBLK_P - 1) / NBLK_P;
    int beg = blockIdx.x * chunk;
    int end = min(beg + chunk, ETOT);
    for (int e = beg + threadIdx.x; e < end; e += 256) {
        int t_ = (e < E_EDGES) ? tgt[e] : (e - E_EDGES);
        atomicAdd(&cnt[t_ / NPB], 1);
    }
    __syncthreads();
    if (threadIdx.x < NB) gcount[blockIdx.x * NB + threadIdx.x] = cnt[threadIdx.x];
}

// parallel scan over NBLK_P block-counts x NB buckets (1 block, 512 threads)
__global__ __launch_bounds__(512) void part_scan_kernel(const int* __restrict__ gcount,
                                                        int* __restrict__ goff,
                                                        int* __restrict__ bcnt) {
    __shared__ int arr[NBLK_P][NB];
    int k = threadIdx.x;
    int4 a = ((const int4*)gcount)[k * 2];
    int4 b = ((const int4*)gcount)[k * 2 + 1];
    int own[NB] = {a.x, a.y, a.z, a.w, b.x, b.y, b.z, b.w};
    #pragma unroll
    for (int j = 0; j < NB; j++) arr[k][j] = own[j];
    __syncthreads();
    for (int off = 1; off < NBLK_P; off <<= 1) {
        int tmp[NB];
        #pragma unroll
        for (int j = 0; j < NB; j++) tmp[j] = (k >= off) ? arr[k - off][j] : 0;
        __syncthreads();
        #pragma unroll
        for (int j = 0; j < NB; j++) arr[k][j] += tmp[j];
        __syncthreads();
    }
    int ex[NB];
    #pragma unroll
    for (int j = 0; j < NB; j++) ex[j] = arr[k][j] - own[j];   // exclusive
    ((int4*)goff)[k * 2]     = make_int4(ex[0], ex[1], ex[2], ex[3]);
    ((int4*)goff)[k * 2 + 1] = make_int4(ex[4], ex[5], ex[6], ex[7]);
    if (k == NBLK_P - 1) {
        #pragma unroll
        for (int j = 0; j < NB; j++) bcnt[j] = arr[k][j];
    }
}

__global__ __launch_bounds__(256) void part_scatter_kernel(const int* __restrict__ src,
                                                           const int* __restrict__ tgt,
                                                           const int* __restrict__ goff,
                                                           ull* __restrict__ bpart) {
    __shared__ int cur[NB];
    if (threadIdx.x < NB) cur[threadIdx.x] = goff[blockIdx.x * NB + threadIdx.x];
    __syncthreads();
    const int chunk = (ETOT + NBLK_P - 1) / NBLK_P;
    int beg = blockIdx.x * chunk;
    int end = min(beg + chunk, ETOT);
    for (int e = beg + threadIdx.x; e < end; e += 256) {
        int s_, t_;
        if (e < E_EDGES) { s_ = src[e]; t_ = tgt[e]; }
        else             { s_ = t_ = e - E_EDGES; }
        int b = t_ / NPB;
        int pos = atomicAdd(&cur[b], 1);
        bpart[(size_t)b * BCAP + pos] = ((ull)(unsigned)t_ << 32) | (unsigned)s_;
    }
}

// per-bucket degree count (blockIdx%8 = bucket -> XCD-local counts lines)
__global__ __launch_bounds__(256) void count_edges_kernel(const ull* __restrict__ bpart,
                                                          const int* __restrict__ bcnt,
                                                          int* counts) {
    int b = blockIdx.x & (NB - 1);
    int ib = blockIdx.x >> 3;
    int nblk = gridDim.x >> 3;
    int nb = bcnt[b];
    const ull* bp = bpart + (size_t)b * BCAP;
    for (int i = ib * 256 + threadIdx.x; i < nb; i += nblk * 256)
        atomicAdd(&counts[(int)(bp[i] >> 32)], 1);
}

// ---------------- parallel scan of padded counts (3 tiny kernels) ----------
__global__ __launch_bounds__(256) void scan1_kernel(const int* __restrict__ counts,
                                                    int* __restrict__ row_ptr,
                                                    int* __restrict__ bsum) {
    __shared__ int sums[256];
    int t = threadIdx.x;
    int i = blockIdx.x * 256 + t;
    int c = (i < N_NODES) ? ((counts[i] + 7) & ~7) : 0;
    sums[t] = c;
    __syncthreads();
    for (int off = 1; off < 256; off <<= 1) {
        int a = sums[t];
        int u = (t >= off) ? sums[t - off] : 0;
        __syncthreads();
        sums[t] = a + u;
        __syncthreads();
    }
    if (i < N_NODES) row_ptr[i] = sums[t] - c;   // local exclusive
    if (t == 255) bsum[blockIdx.x] = sums[255];
}

__global__ __launch_bounds__(256) void scan2_kernel(const int* __restrict__ bsum,
                                                    int* __restrict__ boff,
                                                    int* __restrict__ row_ptr) {
    __shared__ int sums[256];
    int t = threadIdx.x;
    int b = (t < NBLK_S) ? bsum[t] : 0;
    sums[t] = b;
    __syncthreads();
    for (int off = 1; off < 256; off <<= 1) {
        int a = sums[t];
        int u = (t >= off) ? sums[t - off] : 0;
        __syncthreads();
        sums[t] = a + u;
        __syncthreads();
    }
    if (t < NBLK_S) boff[t] = sums[t] - b;
    if (t == 255) row_ptr[N_NODES] = sums[255];
}

__global__ __launch_bounds__(256) void scan3_kernel(int* __restrict__ row_ptr,
                                                    const int* __restrict__ boff,
                                                    int* __restrict__ cursor) {
    int i = blockIdx.x * 256 + threadIdx.x;
    if (i >= N_NODES) return;
    int v = row_ptr[i] + boff[blockIdx.x];
    row_ptr[i] = v;
    cursor[i]  = v;
}

// per-bucket scatter into col (cursor + col lines XCD-local)
__global__ __launch_bounds__(256) void fill_edges_kernel(const ull* __restrict__ bpart,
                                                         const int* __restrict__ bcnt,
                                                         int* cursor, int* __restrict__ col) {
    int b = blockIdx.x & (NB - 1);
    int ib = blockIdx.x >> 3;
    int nblk = gridDim.x >> 3;
    int nb = bcnt[b];
    const ull* bp = bpart + (size_t)b * BCAP;
    for (int i = ib * 256 + threadIdx.x; i < nb; i += nblk * 256) {
        ull pk = bp[i];
        int t_ = (int)(pk >> 32);
        int s_ = (int)pk;
        int pos = atomicAdd(&cursor[t_], 1);
        col[pos] = s_;
    }
}

// fill pad slots with the row's own node id (valid index; ex forced 0 later)
__global__ __launch_bounds__(256) void pad_edges_kernel(const int* __restrict__ cursor,
                                                        const int* __restrict__ row_ptr,
                                                        int* __restrict__ col) {
    int i = blockIdx.x * 256 + threadIdx.x;
    if (i >= N_NODES) return;
    int e = cursor[i];            // true end after fill
    int pe = row_ptr[i + 1];      // padded end
    for (; e < pe; e++) col[e] = i;
}

// ---------------------------------------------------------------- fp32 -> fp16 casts

__global__ __launch_bounds__(256) void cast_x_kernel(const float* __restrict__ x, _Float16* __restrict__ xh) {
    int i = blockIdx.x * 256 + threadIdx.x;          // over 50000*40 half8s
    if (i >= N_NODES * (KP1 / 8)) return;
    int r = i / (KP1 / 8), c8 = i % (KP1 / 8);
    half8 o;
    const float4* xr = (const float4*)(x + (size_t)r * IN_DIM);
    if (c8 < 37) {
        float4 u = xr[c8 * 2], v = xr[c8 * 2 + 1];
        o[0] = (_Float16)u.x; o[1] = (_Float16)u.y; o[2] = (_Float16)u.z; o[3] = (_Float16)u.w;
        o[4] = (_Float16)v.x; o[5] = (_Float16)v.y; o[6] = (_Float16)v.z; o[7] = (_Float16)v.w;
    } else if (c8 == 37) {
        float4 u = xr[74];
        o[0] = (_Float16)u.x; o[1] = (_Float16)u.y; o[2] = (_Float16)u.z; o[3] = (_Float16)u.w;
        o[4] = o[5] = o[6] = o[7] = (_Float16)0.f;
    } else {
        #pragma unroll
        for (int j = 0; j < 8; j++) o[j] = (_Float16)0.f;
    }
    ((half8*)xh)[i] = o;
}

__global__ __launch_bounds__(256) void cast_w1_kernel(const float* __restrict__ W, _Float16* __restrict__ Wt) {
    int i = blockIdx.x * 256 + threadIdx.x;
    if (i >= HID * KP1) return;
    int n = i / KP1, k = i % KP1;
    float v = (k < IN_DIM) ? W[(size_t)k * HID + n] : 0.f;
    Wt[i] = (_Float16)v;
}

__global__ __launch_bounds__(256) void cast_wc_kernel(const float* __restrict__ W, _Float16* __restrict__ Wt) {
    int i = blockIdx.x * 256 + threadIdx.x;
    if (i >= LAYERS * HID * HID) return;
    int l = i / (HID * HID);
    int r = i % (HID * HID);
    int n = r / HID, k = r % HID;
    Wt[i] = (_Float16)W[(size_t)l * HID * HID + (size_t)k * HID + n];
}

// ---------------------------------------------------------------- fp16 MFMA GEMM
__global__ __launch_bounds__(256) void gemm_mfma_kernel(const _Float16* __restrict__ A,
                                                        const _Float16* __restrict__ Wt,
                                                        const float* __restrict__ bias,
                                                        _Float16* __restrict__ C,
                                                        int M, int Kp, int addbias) {
    __shared__ _Float16 As[128][32];
    __shared__ _Float16 Bs[128][32];
    const int tid = threadIdx.x;
    const int m0 = blockIdx.x * 128;
    const int n0 = blockIdx.y * 128;
    const int w = tid >> 6, lane = tid & 63;
    const int wm = (w & 1) * 64, wn = (w >> 1) * 64;
    const int quad = lane >> 4, m16 = lane & 15;

    f32x4 acc[4][4];
    #pragma unroll
    for (int i = 0; i < 4; i++)
        #pragma unroll
        for (int j = 0; j < 4; j++)
            acc[i][j] = (f32x4){0.f, 0.f, 0.f, 0.f};

    char* lA = (char*)&As[0][0] + w * 1024;   // wave-uniform LDS bases
    char* lB = (char*)&Bs[0][0] + w * 1024;

    for (int k0 = 0; k0 < Kp; k0 += 32) {
        #pragma unroll
        for (int i = 0; i < 2; i++) {
            int seg = tid + i * 256;
            int row = seg >> 2, off = seg & 3;
            GLDS16(&A[(size_t)(m0 + row) * Kp + k0 + off * 8], lA + i * 4096);
            GLDS16(&Wt[(size_t)(n0 + row) * Kp + k0 + off * 8], lB + i * 4096);
        }
        __syncthreads();

        half8 af[4], bf[4];
        #pragma unroll
        for (int i = 0; i < 4; i++) {
            af[i] = *(const half8*)&As[wm + i * 16 + m16][quad * 8];
            bf[i] = *(const half8*)&Bs[wn + i * 16 + m16][quad * 8];
        }
        #pragma unroll
        for (int mi = 0; mi < 4; mi++)
            #pragma unroll
            for (int ni = 0; ni < 4; ni++)
                acc[mi][ni] = __builtin_amdgcn_mfma_f32_16x16x32_f16(af[mi], bf[ni], acc[mi][ni], 0, 0, 0);
        __syncthreads();
    }

    #pragma unroll
    for (int mi = 0; mi < 4; mi++) {
        #pragma unroll
        for (int r = 0; r < 4; r++) {
            int row = m0 + wm + mi * 16 + quad * 4 + r;
            if (row < M) {
                #pragma unroll
                for (int ni = 0; ni < 4; ni++) {
                    int colg = n0 + wn + ni * 16 + m16;
                    float v = acc[mi][ni][r];
                    if (addbias) v += bias[colg];
                    C[(size_t)row * HID + colg] = (_Float16)v;
                }
            }
        }
    }
}

// ---------------------------------------------------------------- attention scores
// Wave = 8 nodes; lane = (node nd=lane>>3, head hd=lane&7).
__global__ __launch_bounds__(256) void score_kernel(const _Float16* __restrict__ hw,
                                                    const float* __restrict__ att_dst,
                                                    const float* __restrict__ att_src,
                                                    float* __restrict__ s_dst,
                                                    float* __restrict__ s_src) {
    int wv = threadIdx.x >> 6, lane = threadIdx.x & 63;
    int nd = lane >> 3, hd = lane & 7;
    float4 ad[8], as4[8];
    const float4* A4d = (const float4*)att_dst;
    const float4* A4s = (const float4*)att_src;
    #pragma unroll
    for (int j = 0; j < 8; j++) { ad[j] = A4d[hd * 8 + j]; as4[j] = A4s[hd * 8 + j]; }
    const half8* hw8 = (const half8*)hw;
    int nwaves = gridDim.x * 4;
    for (int g = blockIdx.x * 4 + wv; g < N_NODES / 8; g += nwaves) {
        int node = g * 8 + nd;
        float sd = 0.f, ss = 0.f;
        #pragma unroll
        for (int k = 0; k < 4; k++) {
            half8 v = hw8[(size_t)node * 32 + hd * 4 + k];
            #pragma unroll
            for (int i = 0; i < 8; i++) {
                float f = (float)v[i];
                int q = k * 8 + i;
                sd += f * ((const float*)&ad[q >> 2])[q & 3];
                ss += f * ((const float*)&as4[q >> 2])[q & 3];
            }
        }
        s_dst[(size_t)g * 64 + lane] = sd;   // == node*8+hd
        s_src[(size_t)g * 64 + lane] = ss;
    }
}

// ---------------------------------------------------------------- aggregation
// Channel-split: each dispatch handles heads hbase..hbase+3 (channels
// hbase*32..hbase*32+128), gathering 256B half-rows from a 12.8 MB half-table
// to cut L2 reuse distance. Phase A per pass covers only its 4 heads
// (16 slots x 4 heads per wave-iter) => no duplicated exp/s_src work.
__global__ __launch_bounds__(256) void agg_kernel(const int* __restrict__ row_ptr,
                                                  const int* __restrict__ deg_arr,
                                                  const int* __restrict__ col,
                                                  const float* __restrict__ s_dst,
                                                  const float* __restrict__ s_src,
                                                  const _Float16* __restrict__ hw,
                                                  const float* __restrict__ bias,
                                                  _Float16* __restrict__ h_out,
                                                  int hbase) {
    __shared__ float exL[4][DEG_CAP * 4];
    __shared__ int  snL[4][DEG_CAP];

    int wv   = threadIdx.x >> 6;
    int lane = threadIdx.x & 63;
    int t = blockIdx.x * 4 + wv;
    if (t >= N_NODES) return;

    int start = row_ptr[t];
    int pdeg  = row_ptr[t + 1] - start;
    int deg   = deg_arr[t];

    if (pdeg <= DEG_CAP) {
        // ---------- fast path ----------
        // Phase A: 16 slots x 4 heads per iteration
        int sl = lane >> 2;        // slot-in-group 0..15
        int eh = lane & 3;         // head offset within pass
        float sd = s_dst[(size_t)t * HEADS + hbase + eh];
        int pdeg16 = (pdeg + 15) & ~15;
        float dsum = 0.f;
        for (int s0 = 0; s0 < pdeg16; s0 += 16) {
            int slot = s0 + sl;
            int sn = (slot < pdeg) ? col[start + slot] : t;
            float a = sd + s_src[(size_t)sn * HEADS + hbase + eh];
            a = (a > 0.f) ? a : NEG_SLOPE * a;
            float exv = (slot < deg) ? __expf(a) : 0.f;
            exL[wv][slot * 4 + eh] = exv;
            if (eh == 0) snL[wv][slot] = sn;
            dsum += exv;
        }
        dsum += __shfl_xor(dsum, 4);
        dsum += __shfl_xor(dsum, 8);
        dsum += __shfl_xor(dsum, 16);
        dsum += __shfl_xor(dsum, 32);   // lane L holds denom for head hbase+(L&3)

        // Phase C: c = channel-group (8 ch), j = edge sub-slot; 4 edges/instr
        int c = lane & 15, j = lane >> 4;
        int hh = c >> 2;                     // head offset of my channels
        float inv = 1.f / (__shfl(dsum, hh) + 1e-16f);

        const half8* hw8 = (const half8*)hw;
        float acc[8] = {0.f, 0.f, 0.f, 0.f, 0.f, 0.f, 0.f, 0.f};

        for (int s0 = 0; s0 < pdeg16; s0 += 16) {
            int   sns[4];
            half8 v[4];
            float ex[4];
            #pragma unroll
            for (int u = 0; u < 4; u++) sns[u] = snL[wv][s0 + u * 4 + j];
            #pragma unroll
            for (int u = 0; u < 4; u++) v[u] = hw8[(size_t)sns[u] * 32 + hbase * 4 + c];
            #pragma unroll
            for (int u = 0; u < 4; u++) ex[u] = exL[wv][(s0 + u * 4 + j) * 4 + hh];
            #pragma unroll
            for (int u = 0; u < 4; u++)
                #pragma unroll
                for (int i = 0; i < 8; i++)
                    acc[i] += ex[u] * (float)v[u][i];
        }

        #pragma unroll
        for (int i = 0; i < 8; i++) {
            acc[i] += __shfl_xor(acc[i], 16);
            acc[i] += __shfl_xor(acc[i], 32);
        }

        if (j == 0) {
            half8 ov;
            #pragma unroll
            for (int i = 0; i < 8; i++) {
                float o = acc[i] * inv + bias[hbase * 32 + c * 8 + i];
                o = (o > 0.f) ? o : (__expf(o) - 1.f);
                ov[i] = (_Float16)o;
            }
            ((half8*)h_out)[(size_t)t * 32 + hbase * 4 + c] = ov;
        }
    } else {
        // ---------- slow path (pdeg > DEG_CAP; statistically never) ----------
        if (hbase != 0) return;   // pass 0 handles all channels here
        int eh  = lane & 7;
        int ech = lane >> 3;
        float sd = s_dst[(size_t)t * HEADS + eh];
        int end = start + deg;
        float mx = -1e30f;
        for (int base = start; base < end; base += 8) {
            int e = base + ech;
            if (e < end) {
                int sn = col[e];
                float a = sd + s_src[(size_t)sn * HEADS + eh];
                a = (a > 0.f) ? a : NEG_SLOPE * a;
                mx = fmaxf(mx, a);
            }
        }
        mx = fmaxf(mx, __shfl_xor(mx, 8));
        mx = fmaxf(mx, __shfl_xor(mx, 16));
        mx = fmaxf(mx, __shfl_xor(mx, 32));

        float4 acc = {0.f, 0.f, 0.f, 0.f};
        float dsum = 0.f;
        const half4v* hw4 = (const half4v*)hw;
        int chead = lane >> 3;
        for (int base = start; base < end; base += 8) {
            int e = base + ech;
            float exv = 0.f;
            int sn = 0;
            if (e < end) {
                sn = col[e];
                float a = sd + s_src[(size_t)sn * HEADS + eh];
                a = (a > 0.f) ? a : NEG_SLOPE * a;
                exv = __expf(a - mx);
                dsum += exv;
            }
            int cnt = min(8, end - base);
            for (int j2 = 0; j2 < cnt; j2++) {
                float exj = __shfl(exv, j2 * 8 + chead);
                int  snj  = __shfl(sn,  j2 * 8);
                half4v v = hw4[(size_t)snj * 64 + lane];
                acc.x += exj * (float)v[0];
                acc.y += exj * (float)v[1];
                acc.z += exj * (float)v[2];
                acc.w += exj * (float)v[3];
            }
        }
        dsum += __shfl_xor(dsum, 8);
        dsum += __shfl_xor(dsum, 16);
        dsum += __shfl_xor(dsum, 32);
        float den = __shfl(dsum, chead) + 1e-16f;
        float inv = 1.f / den;
        int cb = lane * 4;
        float o[4] = {acc.x * inv + bias[cb + 0], acc.y * inv + bias[cb + 1],
                      acc.z * inv + bias[cb + 2], acc.w * inv + bias[cb + 3]};
        #pragma unroll
        for (int i = 0; i < 4; i++) o[i] = (o[i] > 0.f) ? o[i] : (__expf(o[i]) - 1.f);
        half4v ov;
        ov[0] = (_Float16)o[0]; ov[1] = (_Float16)o[1];
        ov[2] = (_Float16)o[2]; ov[3] = (_Float16)o[3];
        ((half4v*)h_out)[(size_t)t * 64 + lane] = ov;
    }
}

// ---------------------------------------------------------------- head
__global__ __launch_bounds__(256) void head_kernel(const _Float16* __restrict__ h,
                                                   const int* __restrict__ target_mask,
                                                   const float* __restrict__ W,
                                                   const float* __restrict__ b,
                                                   float* __restrict__ out) {
    int s = blockIdx.x;
    int t = threadIdx.x;
    int n0 = target_mask[s * 2 + 0];
    int n1 = target_mask[s * 2 + 1];
    float f0 = (float)h[(size_t)n0 * HID + t];
    float f1 = (float)h[(size_t)n1 * HID + t];
    float a0 = f0 * W[t * 3 + 0] + f1 * W[(t + 256) * 3 + 0];
    float a1 = f0 * W[t * 3 + 1] + f1 * W[(t + 256) * 3 + 1];
    float a2 = f0 * W[t * 3 + 2] + f1 * W[(t + 256) * 3 + 2];
    #pragma unroll
    for (int off = 32; off >= 1; off >>= 1) {
        a0 += __shfl_xor(a0, off);
        a1 += __shfl_xor(a1, off);
        a2 += __shfl_xor(a2, off);
    }
    __shared__ float red[4][3];
    int wv = t >> 6, ln = t & 63;
    if (ln == 0) { red[wv][0] = a0; red[wv][1] = a1; red[wv][2] = a2; }
    __syncthreads();
    if (t < 3) {
        out[s * 3 + t] = red[0][t] + red[1][t] + red[2][t] + red[3][t] + b[t];
    }
}

// ---------------------------------------------------------------- launch

extern "C" void kernel_launch(void* const* d_in, const int* in_sizes, int n_in,
                              void* d_out, int out_size, void* d_ws, size_t ws_size,
                              hipStream_t stream) {
    const float* x        = (const float*)d_in[0];
    const int*   eidx     = (const int*)  d_in[1];
    const int*   tmask    = (const int*)  d_in[2];
    const float* lin1_W   = (const float*)d_in[3];
    const float* lin1_b   = (const float*)d_in[4];
    const float* convs_W  = (const float*)d_in[5];
    const float* att_dst  = (const float*)d_in[6];
    const float* att_src  = (const float*)d_in[7];
    const float* convs_b  = (const float*)d_in[8];
    const float* lin3_W   = (const float*)d_in[9];
    const float* lin3_b   = (const float*)d_in[10];
    float* out = (float*)d_out;

    char* ws = (char*)d_ws;
    size_t off = 0;
    auto alloc = [&](size_t bytes) -> void* {
        void* p = ws + off;
        off = (off + bytes + 255) & ~(size_t)255;
        return p;
    };
    _Float16* xh   = (_Float16*)alloc((size_t)N_PAD * KP1 * 2);
    _Float16* h    = (_Float16*)alloc((size_t)N_PAD * HID * 2);
    _Float16* hw   = (_Float16*)alloc((size_t)N_NODES * HID * 2);
    _Float16* w1t  = (_Float16*)alloc((size_t)HID * KP1 * 2);
    _Float16* wct  = (_Float16*)alloc((size_t)LAYERS * HID * HID * 2);
    float* sdst    = (float*)alloc((size_t)N_NODES * HEADS * 4);
    float* ssrc    = (float*)alloc((size_t)N_NODES * HEADS * 4);
    int*   counts  = (int*)  alloc((size_t)N_NODES * 4);
    int*   rowptr  = (int*)  alloc((size_t)(N_NODES + 1) * 4);
    int*   cursor  = (int*)  alloc((size_t)N_NODES * 4);
    int*   col     = (int*)  alloc((size_t)EPAD * 4);
    ull*   bpart   = (ull*)  alloc((size_t)NB * BCAP * 8);
    int*   bcnt    = (int*)  alloc((size_t)NB * 4);
    int*   gcount  = (int*)  alloc((size_t)NBLK_P * NB * 4);
    int*   goff    = (int*)  alloc((size_t)NBLK_P * NB * 4);
    int*   bsum    = (int*)  alloc((size_t)NBLK_S * 4);
    int*   boff    = (int*)  alloc((size_t)NBLK_S * 4);

    const int* src = eidx;
    const int* tgt = eidx + E_EDGES;

    // CSR build
    hipMemsetAsync(counts, 0, (size_t)N_NODES * 4, stream);
    part_count_kernel<<<NBLK_P, 256, 0, stream>>>(tgt, gcount);
    part_scan_kernel<<<1, NBLK_P, 0, stream>>>(gcount, goff, bcnt);
    part_scatter_kernel<<<NBLK_P, 256, 0, stream>>>(src, tgt, goff, bpart);
    count_edges_kernel<<<256, 256, 0, stream>>>(bpart, bcnt, counts);
    scan1_kernel<<<NBLK_S, 256, 0, stream>>>(counts, rowptr, bsum);
    scan2_kernel<<<1, 256, 0, stream>>>(bsum, boff, rowptr);
    scan3_kernel<<<NBLK_S, 256, 0, stream>>>(rowptr, boff, cursor);
    fill_edges_kernel<<<256, 256, 0, stream>>>(bpart, bcnt, cursor, col);
    pad_edges_kernel<<<(N_NODES + 255) / 256, 256, 0, stream>>>(cursor, rowptr, col);

    // casts
    cast_x_kernel<<<(N_NODES * (KP1 / 8) + 255) / 256, 256, 0, stream>>>(x, xh);
    cast_w1_kernel<<<(HID * KP1 + 255) / 256, 256, 0, stream>>>(lin1_W, w1t);
    cast_wc_kernel<<<(LAYERS * HID * HID + 255) / 256, 256, 0, stream>>>(convs_W, wct);

    // lin1
    gemm_mfma_kernel<<<dim3((N_NODES + 127) / 128, HID / 128), 256, 0, stream>>>(
        xh, w1t, lin1_b, h, N_NODES, KP1, 1);

    for (int l = 0; l < LAYERS; l++) {
        gemm_mfma_kernel<<<dim3((N_NODES + 127) / 128, HID / 128), 256, 0, stream>>>(
            h, wct + (size_t)l * HID * HID, nullptr, hw, N_NODES, HID, 0);
        score_kernel<<<256, 256, 0, stream>>>(
            hw, att_dst + (size_t)l * HEADS * OC, att_src + (size_t)l * HEADS * OC, sdst, ssrc);
        // two sequential channel-half passes (temporal L2 locality)
        agg_kernel<<<(N_NODES + 3) / 4, 256, 0, stream>>>(
            rowptr, counts, col, sdst, ssrc, hw, convs_b + (size_t)l * HID, h, 0);
        agg_kernel<<<(N_NODES + 3) / 4, 256, 0, stream>>>(
            rowptr, counts, col, sdst, ssrc, hw, convs_b + (size_t)l * HID, h, 4);
    }

    head_kernel<<<BSAMP, 256, 0, stream>>>(h, tmask, lin3_W, lin3_b, out);
}

// Round 10
// 941.098 us; speedup vs baseline: 1.0120x; 1.0120x over previous
//
#include <hip/hip_runtime.h>
#include <math.h>

#define N_NODES 50000
#define N_PAD   50048            // padded rows for 128-row GEMM tiles
#define E_EDGES 1600000
#define ETOT    (E_EDGES + N_NODES)
#define EPAD    (E_EDGES + 8 * N_NODES)   // CSR rows padded to multiple of 8
#define IN_DIM  300
#define KP1     320              // IN_DIM padded to mult of 32
#define HID     256
#define HEADS   8
#define OC      32
#define LAYERS  4
#define BSAMP   1024
#define NEG_SLOPE 0.2f
#define DEG_CAP 128              // fast-path max padded degree per node

// XCD-bucketed CSR build
#define NB     8                 // buckets = XCDs
#define NPB    6250              // nodes per bucket (50000/8)
#define BCAP   262144            // per-bucket partition capacity (mean 206k)
#define NBLK_P 512               // partition blocks
#define NBLK_S 196               // scan blocks (50000/256 rounded up)
#define NBLK_B 2048              // bucket count/fill blocks (256 per bucket)

typedef unsigned long long ull;
typedef _Float16 half8 __attribute__((ext_vector_type(8)));
typedef _Float16 half4v __attribute__((ext_vector_type(4)));
typedef float f32x4 __attribute__((ext_vector_type(4)));

#define GLDS16(g, l) __builtin_amdgcn_global_load_lds( \
    (const __attribute__((address_space(1))) void*)(g), \
    (__attribute__((address_space(3))) void*)(l), 16, 0, 0)

// ---------------------------------------------------------------- CSR build
// Two-pass block-local radix partition by tgt bucket. No global atomics.

__global__ __launch_bounds__(256) void part_count_kernel(const int* __restrict__ tgt,
                                                         int* __restrict__ gcount) {
    __shared__ int cnt[NB];
    if (threadIdx.x < NB) cnt[threadIdx.x] = 0;
    __syncthreads();
    const int chunk = (ETOT + NBLK_P - 1) / NBLK_P;
    int beg = blockIdx.x * chunk;
    int end = min(beg + chunk, ETOT);
    for (int e = beg + threadIdx.x; e < end; e += 256) {
        int t_ = (e < E_EDGES) ? tgt[e] : (e - E_EDGES);
        atomicAdd(&cnt[t_ / NPB], 1);
    }
    __syncthreads();
    if (threadIdx.x < NB) gcount[blockIdx.x * NB + threadIdx.x] = cnt[threadIdx.x];
}

// parallel scan over NBLK_P block-counts x NB buckets (1 block, 512 threads)
__global__ __launch_bounds__(512) void part_scan_kernel(const int* __restrict__ gcount,
                                                        int* __restrict__ goff,
                                                        int* __restrict__ bcnt) {
    __shared__ int arr[NBLK_P][NB];
    int k = threadIdx.x;
    int4 a = ((const int4*)gcount)[k * 2];
    int4 b = ((const int4*)gcount)[k * 2 + 1];
    int own[NB] = {a.x, a.y, a.z, a.w, b.x, b.y, b.z, b.w};
    #pragma unroll
    for (int j = 0; j < NB; j++) arr[k][j] = own[j];
    __syncthreads();
    for (int off = 1; off < NBLK_P; off <<= 1) {
        int tmp[NB];
        #pragma unroll
        for (int j = 0; j < NB; j++) tmp[j] = (k >= off) ? arr[k - off][j] : 0;
        __syncthreads();
        #pragma unroll
        for (int j = 0; j < NB; j++) arr[k][j] += tmp[j];
        __syncthreads();
    }
    int ex[NB];
    #pragma unroll
    for (int j = 0; j < NB; j++) ex[j] = arr[k][j] - own[j];   // exclusive
    ((int4*)goff)[k * 2]     = make_int4(ex[0], ex[1], ex[2], ex[3]);
    ((int4*)goff)[k * 2 + 1] = make_int4(ex[4], ex[5], ex[6], ex[7]);
    if (k == NBLK_P - 1) {
        #pragma unroll
        for (int j = 0; j < NB; j++) bcnt[j] = arr[k][j];
    }
}

__global__ __launch_bounds__(256) void part_scatter_kernel(const int* __restrict__ src,
                                                           const int* __restrict__ tgt,
                                                           const int* __restrict__ goff,
                                                           ull* __restrict__ bpart) {
    __shared__ int cur[NB];
    if (threadIdx.x < NB) cur[threadIdx.x] = goff[blockIdx.x * NB + threadIdx.x];
    __syncthreads();
    const int chunk = (ETOT + NBLK_P - 1) / NBLK_P;
    int beg = blockIdx.x * chunk;
    int end = min(beg + chunk, ETOT);
    for (int e = beg + threadIdx.x; e < end; e += 256) {
        int s_, t_;
        if (e < E_EDGES) { s_ = src[e]; t_ = tgt[e]; }
        else             { s_ = t_ = e - E_EDGES; }
        int b = t_ / NPB;
        int pos = atomicAdd(&cur[b], 1);
        bpart[(size_t)b * BCAP + pos] = ((ull)(unsigned)t_ << 32) | (unsigned)s_;
    }
}

// per-bucket degree count (blockIdx%8 = bucket -> XCD-local counts lines)
__global__ __launch_bounds__(256) void count_edges_kernel(const ull* __restrict__ bpart,
                                                          const int* __restrict__ bcnt,
                                                          int* counts) {
    int b = blockIdx.x & (NB - 1);
    int ib = blockIdx.x >> 3;
    int nblk = gridDim.x >> 3;
    int nb = bcnt[b];
    const ull* bp = bpart + (size_t)b * BCAP;
    for (int i = ib * 256 + threadIdx.x; i < nb; i += nblk * 256)
        atomicAdd(&counts[(int)(bp[i] >> 32)], 1);
}

// ---------------- parallel scan of padded counts (3 tiny kernels) ----------
__global__ __launch_bounds__(256) void scan1_kernel(const int* __restrict__ counts,
                                                    int* __restrict__ row_ptr,
                                                    int* __restrict__ bsum) {
    __shared__ int sums[256];
    int t = threadIdx.x;
    int i = blockIdx.x * 256 + t;
    int c = (i < N_NODES) ? ((counts[i] + 7) & ~7) : 0;
    sums[t] = c;
    __syncthreads();
    for (int off = 1; off < 256; off <<= 1) {
        int a = sums[t];
        int u = (t >= off) ? sums[t - off] : 0;
        __syncthreads();
        sums[t] = a + u;
        __syncthreads();
    }
    if (i < N_NODES) row_ptr[i] = sums[t] - c;   // local exclusive
    if (t == 255) bsum[blockIdx.x] = sums[255];
}

__global__ __launch_bounds__(256) void scan2_kernel(const int* __restrict__ bsum,
                                                    int* __restrict__ boff,
                                                    int* __restrict__ row_ptr) {
    __shared__ int sums[256];
    int t = threadIdx.x;
    int b = (t < NBLK_S) ? bsum[t] : 0;
    sums[t] = b;
    __syncthreads();
    for (int off = 1; off < 256; off <<= 1) {
        int a = sums[t];
        int u = (t >= off) ? sums[t - off] : 0;
        __syncthreads();
        sums[t] = a + u;
        __syncthreads();
    }
    if (t < NBLK_S) boff[t] = sums[t] - b;
    if (t == 255) row_ptr[N_NODES] = sums[255];
}

__global__ __launch_bounds__(256) void scan3_kernel(int* __restrict__ row_ptr,
                                                    const int* __restrict__ boff,
                                                    int* __restrict__ cursor) {
    int i = blockIdx.x * 256 + threadIdx.x;
    if (i >= N_NODES) return;
    int v = row_ptr[i] + boff[blockIdx.x];
    row_ptr[i] = v;
    cursor[i]  = v;
}

// per-bucket scatter into col (cursor + col lines XCD-local)
__global__ __launch_bounds__(256) void fill_edges_kernel(const ull* __restrict__ bpart,
                                                         const int* __restrict__ bcnt,
                                                         int* cursor, int* __restrict__ col) {
    int b = blockIdx.x & (NB - 1);
    int ib = blockIdx.x >> 3;
    int nblk = gridDim.x >> 3;
    int nb = bcnt[b];
    const ull* bp = bpart + (size_t)b * BCAP;
    for (int i = ib * 256 + threadIdx.x; i < nb; i += nblk * 256) {
        ull pk = bp[i];
        int t_ = (int)(pk >> 32);
        int s_ = (int)pk;
        int pos = atomicAdd(&cursor[t_], 1);
        col[pos] = s_;
    }
}

// fill pad slots with the row's own node id (valid index; ex forced 0 later)
__global__ __launch_bounds__(256) void pad_edges_kernel(const int* __restrict__ cursor,
                                                        const int* __restrict__ row_ptr,
                                                        int* __restrict__ col) {
    int i = blockIdx.x * 256 + threadIdx.x;
    if (i >= N_NODES) return;
    int e = cursor[i];            // true end after fill
    int pe = row_ptr[i + 1];      // padded end
    for (; e < pe; e++) col[e] = i;
}

// ---------------------------------------------------------------- fp32 -> fp16 casts

__global__ __launch_bounds__(256) void cast_x_kernel(const float* __restrict__ x, _Float16* __restrict__ xh) {
    int i = blockIdx.x * 256 + threadIdx.x;          // over 50000*40 half8s
    if (i >= N_NODES * (KP1 / 8)) return;
    int r = i / (KP1 / 8), c8 = i % (KP1 / 8);
    half8 o;
    const float4* xr = (const float4*)(x + (size_t)r * IN_DIM);
    if (c8 < 37) {
        float4 u = xr[c8 * 2], v = xr[c8 * 2 + 1];
        o[0] = (_Float16)u.x; o[1] = (_Float16)u.y; o[2] = (_Float16)u.z; o[3] = (_Float16)u.w;
        o[4] = (_Float16)v.x; o[5] = (_Float16)v.y; o[6] = (_Float16)v.z; o[7] = (_Float16)v.w;
    } else if (c8 == 37) {
        float4 u = xr[74];
        o[0] = (_Float16)u.x; o[1] = (_Float16)u.y; o[2] = (_Float16)u.z; o[3] = (_Float16)u.w;
        o[4] = o[5] = o[6] = o[7] = (_Float16)0.f;
    } else {
        #pragma unroll
        for (int j = 0; j < 8; j++) o[j] = (_Float16)0.f;
    }
    ((half8*)xh)[i] = o;
}

__global__ __launch_bounds__(256) void cast_w1_kernel(const float* __restrict__ W, _Float16* __restrict__ Wt) {
    int i = blockIdx.x * 256 + threadIdx.x;
    if (i >= HID * KP1) return;
    int n = i / KP1, k = i % KP1;
    float v = (k < IN_DIM) ? W[(size_t)k * HID + n] : 0.f;
    Wt[i] = (_Float16)v;
}

__global__ __launch_bounds__(256) void cast_wc_kernel(const float* __restrict__ W, _Float16* __restrict__ Wt) {
    int i = blockIdx.x * 256 + threadIdx.x;
    if (i >= LAYERS * HID * HID) return;
    int l = i / (HID * HID);
    int r = i % (HID * HID);
    int n = r / HID, k = r % HID;
    Wt[i] = (_Float16)W[(size_t)l * HID * HID + (size_t)k * HID + n];
}

// ---------------------------------------------------------------- fp16 MFMA GEMM
__global__ __launch_bounds__(256) void gemm_mfma_kernel(const _Float16* __restrict__ A,
                                                        const _Float16* __restrict__ Wt,
                                                        const float* __restrict__ bias,
                                                        _Float16* __restrict__ C,
                                                        int M, int Kp, int addbias) {
    __shared__ _Float16 As[128][32];
    __shared__ _Float16 Bs[128][32];
    const int tid = threadIdx.x;
    const int m0 = blockIdx.x * 128;
    const int n0 = blockIdx.y * 128;
    const int w = tid >> 6, lane = tid & 63;
    const int wm = (w & 1) * 64, wn = (w >> 1) * 64;
    const int quad = lane >> 4, m16 = lane & 15;

    f32x4 acc[4][4];
    #pragma unroll
    for (int i = 0; i < 4; i++)
        #pragma unroll
        for (int j = 0; j < 4; j++)
            acc[i][j] = (f32x4){0.f, 0.f, 0.f, 0.f};

    char* lA = (char*)&As[0][0] + w * 1024;   // wave-uniform LDS bases
    char* lB = (char*)&Bs[0][0] + w * 1024;

    for (int k0 = 0; k0 < Kp; k0 += 32) {
        #pragma unroll
        for (int i = 0; i < 2; i++) {
            int seg = tid + i * 256;
            int row = seg >> 2, off = seg & 3;
            GLDS16(&A[(size_t)(m0 + row) * Kp + k0 + off * 8], lA + i * 4096);
            GLDS16(&Wt[(size_t)(n0 + row) * Kp + k0 + off * 8], lB + i * 4096);
        }
        __syncthreads();

        half8 af[4], bf[4];
        #pragma unroll
        for (int i = 0; i < 4; i++) {
            af[i] = *(const half8*)&As[wm + i * 16 + m16][quad * 8];
            bf[i] = *(const half8*)&Bs[wn + i * 16 + m16][quad * 8];
        }
        #pragma unroll
        for (int mi = 0; mi < 4; mi++)
            #pragma unroll
            for (int ni = 0; ni < 4; ni++)
                acc[mi][ni] = __builtin_amdgcn_mfma_f32_16x16x32_f16(af[mi], bf[ni], acc[mi][ni], 0, 0, 0);
        __syncthreads();
    }

    #pragma unroll
    for (int mi = 0; mi < 4; mi++) {
        #pragma unroll
        for (int r = 0; r < 4; r++) {
            int row = m0 + wm + mi * 16 + quad * 4 + r;
            if (row < M) {
                #pragma unroll
                for (int ni = 0; ni < 4; ni++) {
                    int colg = n0 + wn + ni * 16 + m16;
                    float v = acc[mi][ni][r];
                    if (addbias) v += bias[colg];
                    C[(size_t)row * HID + colg] = (_Float16)v;
                }
            }
        }
    }
}

// ---------------------------------------------------------------- attention scores
// Wave = 8 nodes; lane = (node nd=lane>>3, head hd=lane&7).
__global__ __launch_bounds__(256) void score_kernel(const _Float16* __restrict__ hw,
                                                    const float* __restrict__ att_dst,
                                                    const float* __restrict__ att_src,
                                                    float* __restrict__ s_dst,
                                                    float* __restrict__ s_src) {
    int wv = threadIdx.x >> 6, lane = threadIdx.x & 63;
    int nd = lane >> 3, hd = lane & 7;
    float4 ad[8], as4[8];
    const float4* A4d = (const float4*)att_dst;
    const float4* A4s = (const float4*)att_src;
    #pragma unroll
    for (int j = 0; j < 8; j++) { ad[j] = A4d[hd * 8 + j]; as4[j] = A4s[hd * 8 + j]; }
    const half8* hw8 = (const half8*)hw;
    int nwaves = gridDim.x * 4;
    for (int g = blockIdx.x * 4 + wv; g < N_NODES / 8; g += nwaves) {
        int node = g * 8 + nd;
        float sd = 0.f, ss = 0.f;
        #pragma unroll
        for (int k = 0; k < 4; k++) {
            half8 v = hw8[(size_t)node * 32 + hd * 4 + k];
            #pragma unroll
            for (int i = 0; i < 8; i++) {
                float f = (float)v[i];
                int q = k * 8 + i;
                sd += f * ((const float*)&ad[q >> 2])[q & 3];
                ss += f * ((const float*)&as4[q >> 2])[q & 3];
            }
        }
        s_dst[(size_t)g * 64 + lane] = sd;   // == node*8+hd
        s_src[(size_t)g * 64 + lane] = ss;
    }
}

// ---------------------------------------------------------------- aggregation
// Single-pass (R8): no max-subtraction; phase A -> ex into LDS + denom;
// phase C pure gather+fma, 4 edges x 1KB per wave-instr group.
__global__ __launch_bounds__(256) void agg_kernel(const int* __restrict__ row_ptr,
                                                  const int* __restrict__ deg_arr,
                                                  const int* __restrict__ col,
                                                  const float* __restrict__ s_dst,
                                                  const float* __restrict__ s_src,
                                                  const _Float16* __restrict__ hw,
                                                  const float* __restrict__ bias,
                                                  _Float16* __restrict__ h_out) {
    __shared__ float exL[4][DEG_CAP * 8];
    __shared__ int  snL[4][DEG_CAP];

    int wv   = threadIdx.x >> 6;
    int lane = threadIdx.x & 63;
    int t = blockIdx.x * 4 + wv;
    if (t >= N_NODES) return;

    int start = row_ptr[t];
    int pdeg  = row_ptr[t + 1] - start;
    int deg   = deg_arr[t];

    int eh  = lane & 7;        // head (phase A)
    int ech = lane >> 3;       // edge slot within group (phase A)
    float sd = s_dst[(size_t)t * HEADS + eh];

    if (pdeg <= DEG_CAP) {
        // ---------- fast path ----------
        int ngrp = pdeg >> 3;
        float dsum = 0.f;
        for (int g = 0; g < ngrp; g++) {
            int slot = g * 8 + ech;
            int sn = col[start + slot];
            float a = sd + s_src[(size_t)sn * HEADS + eh];
            a = (a > 0.f) ? a : NEG_SLOPE * a;
            float exv = (slot < deg) ? __expf(a) : 0.f;
            exL[wv][slot * 8 + eh] = exv;
            if (eh == 0) snL[wv][slot] = sn;
            dsum += exv;
        }
        dsum += __shfl_xor(dsum, 8);
        dsum += __shfl_xor(dsum, 16);
        dsum += __shfl_xor(dsum, 32);   // lanes with eh==h hold denom_h

        int p  = lane >> 5;          // edge parity
        int c  = lane & 31;          // channel group (8 channels)
        int hh = c >> 2;             // head of my channels
        float inv = 1.f / (__shfl(dsum, hh) + 1e-16f);

        const half8* hw8 = (const half8*)hw;
        float acc[8] = {0.f, 0.f, 0.f, 0.f, 0.f, 0.f, 0.f, 0.f};

        for (int g = 0; g < ngrp; g++) {
            int base = g * 8;
            int   sns[4];
            half8 v[4];
            float ex[4];
            #pragma unroll
            for (int j = 0; j < 4; j++) sns[j] = snL[wv][base + 2 * j + p];
            #pragma unroll
            for (int j = 0; j < 4; j++) v[j] = hw8[(size_t)sns[j] * 32 + c];
            #pragma unroll
            for (int j = 0; j < 4; j++) ex[j] = exL[wv][(base + 2 * j + p) * 8 + hh];
            #pragma unroll
            for (int j = 0; j < 4; j++)
                #pragma unroll
                for (int i = 0; i < 8; i++)
                    acc[i] += ex[j] * (float)v[j][i];
        }

        #pragma unroll
        for (int i = 0; i < 8; i++) acc[i] += __shfl_xor(acc[i], 32);

        if (p == 0) {
            half8 ov;
            #pragma unroll
            for (int i = 0; i < 8; i++) {
                float o = acc[i] * inv + bias[c * 8 + i];
                o = (o > 0.f) ? o : (__expf(o) - 1.f);
                ov[i] = (_Float16)o;
            }
            ((half8*)h_out)[(size_t)t * 32 + c] = ov;
        }
    } else {
        // ---------- slow path (pdeg > DEG_CAP; statistically never) ----------
        int end = start + deg;
        float mx = -1e30f;
        for (int base = start; base < end; base += 8) {
            int e = base + ech;
            if (e < end) {
                int sn = col[e];
                float a = sd + s_src[(size_t)sn * HEADS + eh];
                a = (a > 0.f) ? a : NEG_SLOPE * a;
                mx = fmaxf(mx, a);
            }
        }
        mx = fmaxf(mx, __shfl_xor(mx, 8));
        mx = fmaxf(mx, __shfl_xor(mx, 16));
        mx = fmaxf(mx, __shfl_xor(mx, 32));

        float4 acc = {0.f, 0.f, 0.f, 0.f};
        float dsum = 0.f;
        const half4v* hw4 = (const half4v*)hw;
        int chead = lane >> 3;
        for (int base = start; base < end; base += 8) {
            int e = base + ech;
            float exv = 0.f;
            int sn = 0;
            if (e < end) {
                sn = col[e];
                float a = sd + s_src[(size_t)sn * HEADS + eh];
                a = (a > 0.f) ? a : NEG_SLOPE * a;
                exv = __expf(a - mx);
                dsum += exv;
            }
            int cnt = min(8, end - base);
            for (int j = 0; j < cnt; j++) {
                float exj = __shfl(exv, j * 8 + chead);
                int  snj  = __shfl(sn,  j * 8);
                half4v v = hw4[(size_t)snj * 64 + lane];
                acc.x += exj * (float)v[0];
                acc.y += exj * (float)v[1];
                acc.z += exj * (float)v[2];
                acc.w += exj * (float)v[3];
            }
        }
        dsum += __shfl_xor(dsum, 8);
        dsum += __shfl_xor(dsum, 16);
        dsum += __shfl_xor(dsum, 32);
        float den = __shfl(dsum, chead) + 1e-16f;
        float inv = 1.f / den;
        int cb = lane * 4;
        float o[4] = {acc.x * inv + bias[cb + 0], acc.y * inv + bias[cb + 1],
                      acc.z * inv + bias[cb + 2], acc.w * inv + bias[cb + 3]};
        #pragma unroll
        for (int i = 0; i < 4; i++) o[i] = (o[i] > 0.f) ? o[i] : (__expf(o[i]) - 1.f);
        half4v ov;
        ov[0] = (_Float16)o[0]; ov[1] = (_Float16)o[1];
        ov[2] = (_Float16)o[2]; ov[3] = (_Float16)o[3];
        ((half4v*)h_out)[(size_t)t * 64 + lane] = ov;
    }
}

// ---------------------------------------------------------------- head
__global__ __launch_bounds__(256) void head_kernel(const _Float16* __restrict__ h,
                                                   const int* __restrict__ target_mask,
                                                   const float* __restrict__ W,
                                                   const float* __restrict__ b,
                                                   float* __restrict__ out) {
    int s = blockIdx.x;
    int t = threadIdx.x;
    int n0 = target_mask[s * 2 + 0];
    int n1 = target_mask[s * 2 + 1];
    float f0 = (float)h[(size_t)n0 * HID + t];
    float f1 = (float)h[(size_t)n1 * HID + t];
    float a0 = f0 * W[t * 3 + 0] + f1 * W[(t + 256) * 3 + 0];
    float a1 = f0 * W[t * 3 + 1] + f1 * W[(t + 256) * 3 + 1];
    float a2 = f0 * W[t * 3 + 2] + f1 * W[(t + 256) * 3 + 2];
    #pragma unroll
    for (int off = 32; off >= 1; off >>= 1) {
        a0 += __shfl_xor(a0, off);
        a1 += __shfl_xor(a1, off);
        a2 += __shfl_xor(a2, off);
    }
    __shared__ float red[4][3];
    int wv = t >> 6, ln = t & 63;
    if (ln == 0) { red[wv][0] = a0; red[wv][1] = a1; red[wv][2] = a2; }
    __syncthreads();
    if (t < 3) {
        out[s * 3 + t] = red[0][t] + red[1][t] + red[2][t] + red[3][t] + b[t];
    }
}

// ---------------------------------------------------------------- launch

extern "C" void kernel_launch(void* const* d_in, const int* in_sizes, int n_in,
                              void* d_out, int out_size, void* d_ws, size_t ws_size,
                              hipStream_t stream) {
    const float* x        = (const float*)d_in[0];
    const int*   eidx     = (const int*)  d_in[1];
    const int*   tmask    = (const int*)  d_in[2];
    const float* lin1_W   = (const float*)d_in[3];
    const float* lin1_b   = (const float*)d_in[4];
    const float* convs_W  = (const float*)d_in[5];
    const float* att_dst  = (const float*)d_in[6];
    const float* att_src  = (const float*)d_in[7];
    const float* convs_b  = (const float*)d_in[8];
    const float* lin3_W   = (const float*)d_in[9];
    const float* lin3_b   = (const float*)d_in[10];
    float* out = (float*)d_out;

    char* ws = (char*)d_ws;
    size_t off = 0;
    auto alloc = [&](size_t bytes) -> void* {
        void* p = ws + off;
        off = (off + bytes + 255) & ~(size_t)255;
        return p;
    };
    _Float16* xh   = (_Float16*)alloc((size_t)N_PAD * KP1 * 2);
    _Float16* h    = (_Float16*)alloc((size_t)N_PAD * HID * 2);
    _Float16* hw   = (_Float16*)alloc((size_t)N_NODES * HID * 2);
    _Float16* w1t  = (_Float16*)alloc((size_t)HID * KP1 * 2);
    _Float16* wct  = (_Float16*)alloc((size_t)LAYERS * HID * HID * 2);
    float* sdst    = (float*)alloc((size_t)N_NODES * HEADS * 4);
    float* ssrc    = (float*)alloc((size_t)N_NODES * HEADS * 4);
    int*   counts  = (int*)  alloc((size_t)N_NODES * 4);
    int*   rowptr  = (int*)  alloc((size_t)(N_NODES + 1) * 4);
    int*   cursor  = (int*)  alloc((size_t)N_NODES * 4);
    int*   col     = (int*)  alloc((size_t)EPAD * 4);
    ull*   bpart   = (ull*)  alloc((size_t)NB * BCAP * 8);
    int*   bcnt    = (int*)  alloc((size_t)NB * 4);
    int*   gcount  = (int*)  alloc((size_t)NBLK_P * NB * 4);
    int*   goff    = (int*)  alloc((size_t)NBLK_P * NB * 4);
    int*   bsum    = (int*)  alloc((size_t)NBLK_S * 4);
    int*   boff    = (int*)  alloc((size_t)NBLK_S * 4);

    const int* src = eidx;
    const int* tgt = eidx + E_EDGES;

    // CSR build
    hipMemsetAsync(counts, 0, (size_t)N_NODES * 4, stream);
    part_count_kernel<<<NBLK_P, 256, 0, stream>>>(tgt, gcount);
    part_scan_kernel<<<1, NBLK_P, 0, stream>>>(gcount, goff, bcnt);
    part_scatter_kernel<<<NBLK_P, 256, 0, stream>>>(src, tgt, goff, bpart);
    count_edges_kernel<<<NBLK_B, 256, 0, stream>>>(bpart, bcnt, counts);
    scan1_kernel<<<NBLK_S, 256, 0, stream>>>(counts, rowptr, bsum);
    scan2_kernel<<<1, 256, 0, stream>>>(bsum, boff, rowptr);
    scan3_kernel<<<NBLK_S, 256, 0, stream>>>(rowptr, boff, cursor);
    fill_edges_kernel<<<NBLK_B, 256, 0, stream>>>(bpart, bcnt, cursor, col);
    pad_edges_kernel<<<(N_NODES + 255) / 256, 256, 0, stream>>>(cursor, rowptr, col);

    // casts
    cast_x_kernel<<<(N_NODES * (KP1 / 8) + 255) / 256, 256, 0, stream>>>(x, xh);
    cast_w1_kernel<<<(HID * KP1 + 255) / 256, 256, 0, stream>>>(lin1_W, w1t);
    cast_wc_kernel<<<(LAYERS * HID * HID + 255) / 256, 256, 0, stream>>>(convs_W, wct);

    // lin1
    gemm_mfma_kernel<<<dim3((N_NODES + 127) / 128, HID / 128), 256, 0, stream>>>(
        xh, w1t, lin1_b, h, N_NODES, KP1, 1);

    for (int l = 0; l < LAYERS; l++) {
        gemm_mfma_kernel<<<dim3((N_NODES + 127) / 128, HID / 128), 256, 0, stream>>>(
            h, wct + (size_t)l * HID * HID, nullptr, hw, N_NODES, HID, 0);
        score_kernel<<<256, 256, 0, stream>>>(
            hw, att_dst + (size_t)l * HEADS * OC, att_src + (size_t)l * HEADS * OC, sdst, ssrc);
        agg_kernel<<<(N_NODES + 3) / 4, 256, 0, stream>>>(
            rowptr, counts, col, sdst, ssrc, hw, convs_b + (size_t)l * HID, h);
    }

    head_kernel<<<BSAMP, 256, 0, stream>>>(h, tmask, lin3_W, lin3_b, out);
}